// Round 2
// baseline (1167.731 us; speedup 1.0000x reference)
//
#include <hip/hip_runtime.h>
#include <hip/hip_bf16.h>
#include <stdint.h>

#define E_    8
#define C_    1024
#define H_    4096
#define NTOK  8192
#define CAP   8192
#define MT_MAX 136

typedef __attribute__((ext_vector_type(8))) short bf16x8;
typedef __attribute__((ext_vector_type(4))) float f32x4;

__device__ __forceinline__ ushort f2bf(float f){
  union { float f; uint32_t u; } v; v.f = f;
  uint32_t r = v.u + 0x7fffu + ((v.u >> 16) & 1u);
  return (ushort)(r >> 16);
}

__device__ __forceinline__ void async16(const ushort* g, ushort* l){
  __builtin_amdgcn_global_load_lds(
      (const __attribute__((address_space(1))) void*)g,
      (__attribute__((address_space(3))) void*)l, 16, 0, 0);
}

// ---------------- zero counts ----------------
__global__ void zero_counts(int* counts){
  if (threadIdx.x < E_) counts[threadIdx.x] = 0;
}

// ---------------- gating: scores, softmax, top2, bucket push, out init ----------------
__global__ __launch_bounds__(256) void gate_kernel(
    const float* __restrict__ x, const float* __restrict__ Wg,
    const float* __restrict__ bg, const float* __restrict__ b2,
    float* __restrict__ out, int* __restrict__ counts,
    int* __restrict__ btok, float* __restrict__ bprob)
{
  int wave = threadIdx.x >> 6, lane = threadIdx.x & 63;
  int t = blockIdx.x * 4 + wave;
  const float* xr = x + (size_t)t * C_;

  float s[E_];
  #pragma unroll
  for (int e = 0; e < E_; ++e) s[e] = 0.f;
  for (int j = 0; j < 16; ++j){
    int c = j * 64 + lane;
    float xv = xr[c];
    const float* wr = Wg + c * E_;
    #pragma unroll
    for (int e = 0; e < E_; ++e) s[e] += xv * wr[e];
  }
  #pragma unroll
  for (int e = 0; e < E_; ++e){
    float v = s[e];
    for (int o = 32; o; o >>= 1) v += __shfl_xor(v, o);
    s[e] = v + bg[e];
  }
  // softmax over 8
  float mx = s[0];
  #pragma unroll
  for (int e = 1; e < E_; ++e) mx = fmaxf(mx, s[e]);
  float g[E_]; float sum = 0.f;
  #pragma unroll
  for (int e = 0; e < E_; ++e){ g[e] = expf(s[e] - mx); sum += g[e]; }
  float inv = 1.f / sum;
  #pragma unroll
  for (int e = 0; e < E_; ++e) g[e] *= inv;
  // top-2 (ties -> lower index, matching jax.lax.top_k)
  int e0 = 0; float v0 = g[0];
  #pragma unroll
  for (int e = 1; e < E_; ++e) if (g[e] > v0){ v0 = g[e]; e0 = e; }
  int e1 = -1; float v1 = -1.f;
  #pragma unroll
  for (int e = 0; e < E_; ++e){ if (e == e0) continue; if (g[e] > v1){ v1 = g[e]; e1 = e; } }
  // renormalized softmax over the two selected probabilities
  float q  = expf(v1 - v0);
  float p0 = 1.f / (1.f + q);
  float p1 = q / (1.f + q);

  // out init: out[t,:] = p0*b2[e0,:] + p1*b2[e1,:]
  const float* b2a = b2 + (size_t)e0 * C_;
  const float* b2b = b2 + (size_t)e1 * C_;
  float* orow = out + (size_t)t * C_;
  for (int j = 0; j < 16; ++j){
    int c = j * 64 + lane;
    orow[c] = p0 * b2a[c] + p1 * b2b[c];
  }
  if (lane == 0){
    int p = atomicAdd(&counts[e0], 1);
    btok[e0 * CAP + p] = t; bprob[e0 * CAP + p] = p0;
    p = atomicAdd(&counts[e1], 1);
    btok[e1 * CAP + p] = t; bprob[e1 * CAP + p] = p1;
  }
}

// ---------------- x fp32 -> bf16 ----------------
__global__ __launch_bounds__(256) void conv_x(const float* __restrict__ x, ushort* __restrict__ x16){
  size_t i = ((size_t)blockIdx.x * 256 + threadIdx.x) * 4;
  float4 v = *(const float4*)(x + i);
  ushort4 o;
  o.x = f2bf(v.x); o.y = f2bf(v.y); o.z = f2bf(v.z); o.w = f2bf(v.w);
  *(ushort4*)(x16 + i) = o;
}

// ---------------- W transpose + convert: in fp32 [E][R][S] -> out bf16 [E][S][R] ----------------
__global__ __launch_bounds__(256) void transpose_w(const float* __restrict__ in, ushort* __restrict__ out,
                                                   int R, int S){
  __shared__ float t[64][65];
  int e  = blockIdx.z;
  int s0 = blockIdx.x * 64, r0 = blockIdx.y * 64;
  const float* ip = in  + (size_t)e * R * S;
  ushort*      op = out + (size_t)e * R * S;
  int cr = threadIdx.x >> 6;     // 0..3
  int cc = threadIdx.x & 63;
  #pragma unroll
  for (int i = 0; i < 16; ++i){
    int r = i * 4 + cr;
    t[r][cc] = ip[(size_t)(r0 + r) * S + s0 + cc];
  }
  __syncthreads();
  #pragma unroll
  for (int i = 0; i < 16; ++i){
    int s = i * 4 + cr;
    op[(size_t)(s0 + s) * R + r0 + cc] = f2bf(t[cc][s]);
  }
}

// ---------------- setup: prefix tiles, tile table, bucket padding ----------------
__global__ void setup_kernel(const int* __restrict__ counts, int* __restrict__ meta,
                             int* __restrict__ texp, int* __restrict__ tpos,
                             int* __restrict__ btok, float* __restrict__ bprob){
  __shared__ int toff[E_ + 1];
  if (threadIdx.x == 0){
    int to = 0;
    for (int e = 0; e < E_; ++e){ toff[e] = to; to += (counts[e] + 127) >> 7; }
    toff[E_] = to; meta[0] = to;
  }
  __syncthreads();
  int total = toff[E_];
  for (int i = threadIdx.x; i < MT_MAX; i += 256){
    if (i < total){
      int e = 0;
      while (e < E_ - 1 && i >= toff[e + 1]) ++e;
      texp[i] = e; tpos[i] = (i - toff[e]) * 128;
    } else { texp[i] = 0; tpos[i] = 0; }
  }
  for (int j = threadIdx.x; j < E_ * 128; j += 256){
    int e = j >> 7, r = j & 127;
    int c = counts[e];
    int padded = ((c + 127) >> 7) << 7;
    int pos = c + r;
    if (pos < padded){ btok[e * CAP + pos] = 0; bprob[e * CAP + pos] = 0.f; }
  }
}

// ---------------- GEMM1: h = relu(gather(x16) @ W1[e] + b1[e])  (M=pairs, N=4096, K=1024) ----------------
__global__ __launch_bounds__(256) void gemm1(
    const ushort* __restrict__ x16, const ushort* __restrict__ w1t,
    const float* __restrict__ b1, ushort* __restrict__ h,
    const int* __restrict__ texp, const int* __restrict__ tpos,
    const int* __restrict__ btok, const int* __restrict__ meta)
{
  __shared__ ushort Al[128 * 32];
  __shared__ ushort Bl[128 * 32];
  __shared__ int toks[128];
  int mt = blockIdx.x;
  if (mt >= meta[0]) return;
  int tid = threadIdx.x, lane = tid & 63, wave = tid >> 6;
  int e = texp[mt], pb = tpos[mt];
  int n0 = blockIdx.y * 128;
  if (tid < 128) toks[tid] = btok[e * CAP + pb + tid];
  __syncthreads();

  int wr = wave >> 1, wc = wave & 1;
  int fr = lane & 15, kg = lane >> 4;
  const ushort* Bb = w1t + ((size_t)e * H_ + n0) * C_;

  f32x4 acc[4][4];
  #pragma unroll
  for (int m = 0; m < 4; ++m)
    #pragma unroll
    for (int n = 0; n < 4; ++n) acc[m][n] = 0.f;

  for (int k0 = 0; k0 < C_; k0 += 32){
    #pragma unroll
    for (int i = 0; i < 2; ++i){
      int ch = i * 256 + tid;
      int row = ch >> 2, k8 = ch & 3;
      async16(x16 + (size_t)toks[row] * C_ + k0 + k8 * 8, Al + ch * 8);
    }
    #pragma unroll
    for (int i = 0; i < 2; ++i){
      int ch = i * 256 + tid;
      int col = ch >> 2, k8 = ch & 3;
      async16(Bb + (size_t)col * C_ + k0 + k8 * 8, Bl + ch * 8);
    }
    __syncthreads();
    bf16x8 af[4], bfr[4];
    #pragma unroll
    for (int m = 0; m < 4; ++m) af[m]  = *(const bf16x8*)(Al + (wr * 64 + m * 16 + fr) * 32 + kg * 8);
    #pragma unroll
    for (int n = 0; n < 4; ++n) bfr[n] = *(const bf16x8*)(Bl + (wc * 64 + n * 16 + fr) * 32 + kg * 8);
    #pragma unroll
    for (int m = 0; m < 4; ++m)
      #pragma unroll
      for (int n = 0; n < 4; ++n)
        acc[m][n] = __builtin_amdgcn_mfma_f32_16x16x32_bf16(af[m], bfr[n], acc[m][n], 0, 0, 0);
    __syncthreads();
  }

  int fq = lane >> 4;
  size_t hb = (size_t)mt * 128;
  #pragma unroll
  for (int n = 0; n < 4; ++n){
    int nc = n0 + wc * 64 + n * 16 + fr;
    float bv = b1[(size_t)e * H_ + nc];
    #pragma unroll
    for (int m = 0; m < 4; ++m){
      int rbase = wr * 64 + m * 16 + fq * 4;
      #pragma unroll
      for (int r = 0; r < 4; ++r){
        float v = acc[m][n][r] + bv;
        h[(hb + rbase + r) * H_ + nc] = f2bf(v > 0.f ? v : 0.f);
      }
    }
  }
}

// ---------------- GEMM2: out[tok] += p * (h @ W2[e])  (M=pairs, N=1024, K=4096) ----------------
__global__ __launch_bounds__(256) void gemm2(
    const ushort* __restrict__ h, const ushort* __restrict__ w2t,
    float* __restrict__ out,
    const int* __restrict__ texp, const int* __restrict__ tpos,
    const int* __restrict__ btok, const float* __restrict__ bprob,
    const int* __restrict__ meta)
{
  __shared__ ushort Al[128 * 32];
  __shared__ ushort Bl[128 * 32];
  __shared__ int toks[128];
  __shared__ float probs[128];
  int mt = blockIdx.x;
  if (mt >= meta[0]) return;
  int tid = threadIdx.x, lane = tid & 63, wave = tid >> 6;
  int e = texp[mt], pb = tpos[mt];
  int n0 = blockIdx.y * 128;
  if (tid < 128){
    toks[tid]  = btok[e * CAP + pb + tid];
    probs[tid] = bprob[e * CAP + pb + tid];
  }
  __syncthreads();

  int wr = wave >> 1, wc = wave & 1;
  int fr = lane & 15, kg = lane >> 4;
  const ushort* Bb = w2t + ((size_t)e * C_ + n0) * H_;
  const ushort* Ab = h + (size_t)mt * 128 * H_;

  f32x4 acc[4][4];
  #pragma unroll
  for (int m = 0; m < 4; ++m)
    #pragma unroll
    for (int n = 0; n < 4; ++n) acc[m][n] = 0.f;

  for (int k0 = 0; k0 < H_; k0 += 32){
    #pragma unroll
    for (int i = 0; i < 2; ++i){
      int ch = i * 256 + tid;
      int row = ch >> 2, k8 = ch & 3;
      async16(Ab + (size_t)row * H_ + k0 + k8 * 8, Al + ch * 8);
    }
    #pragma unroll
    for (int i = 0; i < 2; ++i){
      int ch = i * 256 + tid;
      int col = ch >> 2, k8 = ch & 3;
      async16(Bb + (size_t)col * H_ + k0 + k8 * 8, Bl + ch * 8);
    }
    __syncthreads();
    bf16x8 af[4], bfr[4];
    #pragma unroll
    for (int m = 0; m < 4; ++m) af[m]  = *(const bf16x8*)(Al + (wr * 64 + m * 16 + fr) * 32 + kg * 8);
    #pragma unroll
    for (int n = 0; n < 4; ++n) bfr[n] = *(const bf16x8*)(Bl + (wc * 64 + n * 16 + fr) * 32 + kg * 8);
    #pragma unroll
    for (int m = 0; m < 4; ++m)
      #pragma unroll
      for (int n = 0; n < 4; ++n)
        acc[m][n] = __builtin_amdgcn_mfma_f32_16x16x32_bf16(af[m], bfr[n], acc[m][n], 0, 0, 0);
    __syncthreads();
  }

  int fq = lane >> 4;
  #pragma unroll
  for (int n = 0; n < 4; ++n){
    int nc = n0 + wc * 64 + n * 16 + fr;
    #pragma unroll
    for (int m = 0; m < 4; ++m){
      int rbase = wr * 64 + m * 16 + fq * 4;
      #pragma unroll
      for (int r = 0; r < 4; ++r){
        int row = rbase + r;
        atomicAdd(out + (size_t)toks[row] * C_ + nc, probs[row] * acc[m][n][r]);
      }
    }
  }
}

// ---------------- launch ----------------
extern "C" void kernel_launch(void* const* d_in, const int* in_sizes, int n_in,
                              void* d_out, int out_size, void* d_ws, size_t ws_size,
                              hipStream_t stream)
{
  const float* x  = (const float*)d_in[0];
  const float* W1 = (const float*)d_in[1];
  const float* b1 = (const float*)d_in[2];
  const float* W2 = (const float*)d_in[3];
  const float* b2 = (const float*)d_in[4];
  const float* Wg = (const float*)d_in[5];
  const float* bg = (const float*)d_in[6];
  float* out = (float*)d_out;

  char* ws = (char*)d_ws;
  size_t off = 0;
  auto alloc = [&](size_t b){ size_t r = off; off += (b + 4095) & ~(size_t)4095; return r; };
  int*    counts = (int*)   (ws + alloc(E_ * 4));
  int*    meta   = (int*)   (ws + alloc(64));
  int*    texp   = (int*)   (ws + alloc(MT_MAX * 4));
  int*    tpos   = (int*)   (ws + alloc(MT_MAX * 4));
  int*    btok   = (int*)   (ws + alloc((size_t)E_ * CAP * 4));
  float*  bprob  = (float*) (ws + alloc((size_t)E_ * CAP * 4));
  ushort* x16    = (ushort*)(ws + alloc((size_t)NTOK * C_ * 2));
  ushort* w1t    = (ushort*)(ws + alloc((size_t)E_ * C_ * H_ * 2));
  ushort* w2t    = (ushort*)(ws + alloc((size_t)E_ * C_ * H_ * 2));
  ushort* h      = (ushort*)(ws + alloc((size_t)MT_MAX * 128 * H_ * 2));
  (void)ws_size; (void)in_sizes; (void)n_in; (void)out_size;

  zero_counts<<<dim3(1), dim3(64), 0, stream>>>(counts);
  gate_kernel<<<dim3(NTOK / 4), dim3(256), 0, stream>>>(x, Wg, bg, b2, out, counts, btok, bprob);
  conv_x<<<dim3((NTOK * C_) / (4 * 256)), dim3(256), 0, stream>>>(x, x16);
  transpose_w<<<dim3(H_ / 64, C_ / 64, E_), dim3(256), 0, stream>>>(W1, w1t, C_, H_);
  transpose_w<<<dim3(C_ / 64, H_ / 64, E_), dim3(256), 0, stream>>>(W2, w2t, H_, C_);
  setup_kernel<<<dim3(1), dim3(256), 0, stream>>>(counts, meta, texp, tpos, btok, bprob);
  gemm1<<<dim3(MT_MAX, H_ / 128), dim3(256), 0, stream>>>(x16, w1t, b1, h, texp, tpos, btok, meta);
  gemm2<<<dim3(MT_MAX, C_ / 128), dim3(256), 0, stream>>>(h, w2t, out, texp, tpos, btok, bprob, meta);
}

// Round 3
// 1111.821 us; speedup vs baseline: 1.0503x; 1.0503x over previous
//
#include <hip/hip_runtime.h>
#include <hip/hip_bf16.h>
#include <stdint.h>

#define E_    8
#define C_    1024
#define H_    4096
#define NTOK  8192
#define CAP   8192
#define MT_MAX 136

typedef __attribute__((ext_vector_type(8))) short bf16x8;
typedef __attribute__((ext_vector_type(4))) float f32x4;

__device__ __forceinline__ ushort f2bf(float f){
  union { float f; uint32_t u; } v; v.f = f;
  uint32_t r = v.u + 0x7fffu + ((v.u >> 16) & 1u);
  return (ushort)(r >> 16);
}

__device__ __forceinline__ void async16(const ushort* g, ushort* l){
  __builtin_amdgcn_global_load_lds(
      (const __attribute__((address_space(1))) void*)g,
      (__attribute__((address_space(3))) void*)l, 16, 0, 0);
}

// ---------------- zero counts ----------------
__global__ void zero_counts(int* counts){
  if (threadIdx.x < E_) counts[threadIdx.x] = 0;
}

// ---------------- gating: scores, softmax, top2, bucket push, out init, x->bf16 ----------------
__global__ __launch_bounds__(256) void gate_kernel(
    const float* __restrict__ x, const float* __restrict__ Wg,
    const float* __restrict__ bg, const float* __restrict__ b2,
    float* __restrict__ out, int* __restrict__ counts,
    int* __restrict__ btok, float* __restrict__ bprob,
    ushort* __restrict__ x16)
{
  int wave = threadIdx.x >> 6, lane = threadIdx.x & 63;
  int t = blockIdx.x * 4 + wave;
  const float* xr = x + (size_t)t * C_;
  ushort* x16r = x16 + (size_t)t * C_;

  float s[E_];
  #pragma unroll
  for (int e = 0; e < E_; ++e) s[e] = 0.f;
  for (int j = 0; j < 16; ++j){
    int c = j * 64 + lane;
    float xv = xr[c];
    x16r[c] = f2bf(xv);              // fused x fp32->bf16 conversion
    const float* wr = Wg + c * E_;
    #pragma unroll
    for (int e = 0; e < E_; ++e) s[e] += xv * wr[e];
  }
  #pragma unroll
  for (int e = 0; e < E_; ++e){
    float v = s[e];
    for (int o = 32; o; o >>= 1) v += __shfl_xor(v, o);
    s[e] = v + bg[e];
  }
  // softmax over 8
  float mx = s[0];
  #pragma unroll
  for (int e = 1; e < E_; ++e) mx = fmaxf(mx, s[e]);
  float g[E_]; float sum = 0.f;
  #pragma unroll
  for (int e = 0; e < E_; ++e){ g[e] = expf(s[e] - mx); sum += g[e]; }
  float inv = 1.f / sum;
  #pragma unroll
  for (int e = 0; e < E_; ++e) g[e] *= inv;
  // top-2 (ties -> lower index, matching jax.lax.top_k)
  int e0 = 0; float v0 = g[0];
  #pragma unroll
  for (int e = 1; e < E_; ++e) if (g[e] > v0){ v0 = g[e]; e0 = e; }
  int e1 = -1; float v1 = -1.f;
  #pragma unroll
  for (int e = 0; e < E_; ++e){ if (e == e0) continue; if (g[e] > v1){ v1 = g[e]; e1 = e; } }
  // renormalized softmax over the two selected probabilities
  float q  = expf(v1 - v0);
  float p0 = 1.f / (1.f + q);
  float p1 = q / (1.f + q);

  // out init: out[t,:] = p0*b2[e0,:] + p1*b2[e1,:]
  const float* b2a = b2 + (size_t)e0 * C_;
  const float* b2b = b2 + (size_t)e1 * C_;
  float* orow = out + (size_t)t * C_;
  for (int j = 0; j < 16; ++j){
    int c = j * 64 + lane;
    orow[c] = p0 * b2a[c] + p1 * b2b[c];
  }
  if (lane == 0){
    int p = atomicAdd(&counts[e0], 1);
    btok[e0 * CAP + p] = t; bprob[e0 * CAP + p] = p0;
    p = atomicAdd(&counts[e1], 1);
    btok[e1 * CAP + p] = t; bprob[e1 * CAP + p] = p1;
  }
}

// ---------------- W transpose + convert: in fp32 [E][R][S] -> out bf16 [E][S][R] ----------------
__global__ __launch_bounds__(256) void transpose_w(const float* __restrict__ in, ushort* __restrict__ out,
                                                   int R, int S){
  __shared__ float t[64][65];
  int e  = blockIdx.z;
  int s0 = blockIdx.x * 64, r0 = blockIdx.y * 64;
  const float* ip = in  + (size_t)e * R * S;
  ushort*      op = out + (size_t)e * R * S;
  int cr = threadIdx.x >> 6;     // 0..3
  int cc = threadIdx.x & 63;
  #pragma unroll
  for (int i = 0; i < 16; ++i){
    int r = i * 4 + cr;
    t[r][cc] = ip[(size_t)(r0 + r) * S + s0 + cc];
  }
  __syncthreads();
  #pragma unroll
  for (int i = 0; i < 16; ++i){
    int s = i * 4 + cr;
    op[(size_t)(s0 + s) * R + r0 + cc] = f2bf(t[cc][s]);
  }
}

// ---------------- setup: prefix tiles, tile table, bucket padding ----------------
__global__ void setup_kernel(const int* __restrict__ counts, int* __restrict__ meta,
                             int* __restrict__ texp, int* __restrict__ tpos,
                             int* __restrict__ btok, float* __restrict__ bprob){
  __shared__ int toff[E_ + 1];
  if (threadIdx.x == 0){
    int to = 0;
    for (int e = 0; e < E_; ++e){ toff[e] = to; to += (counts[e] + 127) >> 7; }
    toff[E_] = to; meta[0] = to;
  }
  __syncthreads();
  int total = toff[E_];
  for (int i = threadIdx.x; i < MT_MAX; i += 256){
    if (i < total){
      int e = 0;
      while (e < E_ - 1 && i >= toff[e + 1]) ++e;
      texp[i] = e; tpos[i] = (i - toff[e]) * 128;
    } else { texp[i] = 0; tpos[i] = 0; }
  }
  for (int j = threadIdx.x; j < E_ * 128; j += 256){
    int e = j >> 7, r = j & 127;
    int c = counts[e];
    int padded = ((c + 127) >> 7) << 7;
    int pos = c + r;
    if (pos < padded){ btok[e * CAP + pos] = 0; bprob[e * CAP + pos] = 0.f; }
  }
}

// ---------------- GEMM1: h = relu(gather(x16) @ W1[e] + b1[e])  (M=pairs, N=4096, K=1024) ----------------
// double-buffered LDS, prefetch-before-compute, one barrier per K-step (T3-minimum)
__global__ __launch_bounds__(256) void gemm1(
    const ushort* __restrict__ x16, const ushort* __restrict__ w1t,
    const float* __restrict__ b1, ushort* __restrict__ h,
    const int* __restrict__ texp, const int* __restrict__ tpos,
    const int* __restrict__ btok, const int* __restrict__ meta)
{
  __shared__ ushort Al[2][128 * 32];
  __shared__ ushort Bl[2][128 * 32];
  __shared__ int toks[128];
  int mt = blockIdx.x;
  if (mt >= meta[0]) return;
  int tid = threadIdx.x, lane = tid & 63, wave = tid >> 6;
  int e = texp[mt], pb = tpos[mt];
  int n0 = blockIdx.y * 128;
  if (tid < 128) toks[tid] = btok[e * CAP + pb + tid];
  __syncthreads();

  int wr = wave >> 1, wc = wave & 1;
  int fr = lane & 15, kg = lane >> 4;
  const ushort* Bb = w1t + ((size_t)e * H_ + n0) * C_;

  // hoisted, iteration-invariant staging pointers (2 chunks each of A,B per thread)
  const ushort* pA[2]; const ushort* pB[2];
  #pragma unroll
  for (int i = 0; i < 2; ++i){
    int ch = i * 256 + tid;
    pA[i] = x16 + (size_t)toks[ch >> 2] * C_ + (ch & 3) * 8;
    pB[i] = Bb  + (size_t)(ch >> 2)     * C_ + (ch & 3) * 8;
  }

  f32x4 acc[4][4];
  #pragma unroll
  for (int m = 0; m < 4; ++m)
    #pragma unroll
    for (int n = 0; n < 4; ++n) acc[m][n] = 0.f;

  // prologue: stage tile 0 into buffer 0
  #pragma unroll
  for (int i = 0; i < 2; ++i){
    int ch = i * 256 + tid;
    async16(pA[i], &Al[0][ch * 8]);
    async16(pB[i], &Bl[0][ch * 8]);
  }
  __syncthreads();                       // vmcnt(0): tile 0 resident

  const int NT = C_ / 32;
  int cur = 0;
  for (int t = 0; t < NT - 1; ++t){
    int k0n = (t + 1) * 32;
    // prefetch next tile into the other buffer (overlaps with compute below)
    #pragma unroll
    for (int i = 0; i < 2; ++i){
      int ch = i * 256 + tid;
      async16(pA[i] + k0n, &Al[cur ^ 1][ch * 8]);
      async16(pB[i] + k0n, &Bl[cur ^ 1][ch * 8]);
    }
    // compute current tile
    bf16x8 af[4], bfr[4];
    #pragma unroll
    for (int m = 0; m < 4; ++m) af[m]  = *(const bf16x8*)(&Al[cur][(wr * 64 + m * 16 + fr) * 32 + kg * 8]);
    #pragma unroll
    for (int n = 0; n < 4; ++n) bfr[n] = *(const bf16x8*)(&Bl[cur][(wc * 64 + n * 16 + fr) * 32 + kg * 8]);
    #pragma unroll
    for (int m = 0; m < 4; ++m)
      #pragma unroll
      for (int n = 0; n < 4; ++n)
        acc[m][n] = __builtin_amdgcn_mfma_f32_16x16x32_bf16(af[m], bfr[n], acc[m][n], 0, 0, 0);
    __syncthreads();                     // drains vmcnt(0): next tile resident
    cur ^= 1;
  }
  { // final tile
    bf16x8 af[4], bfr[4];
    #pragma unroll
    for (int m = 0; m < 4; ++m) af[m]  = *(const bf16x8*)(&Al[cur][(wr * 64 + m * 16 + fr) * 32 + kg * 8]);
    #pragma unroll
    for (int n = 0; n < 4; ++n) bfr[n] = *(const bf16x8*)(&Bl[cur][(wc * 64 + n * 16 + fr) * 32 + kg * 8]);
    #pragma unroll
    for (int m = 0; m < 4; ++m)
      #pragma unroll
      for (int n = 0; n < 4; ++n)
        acc[m][n] = __builtin_amdgcn_mfma_f32_16x16x32_bf16(af[m], bfr[n], acc[m][n], 0, 0, 0);
  }

  int fq = lane >> 4;
  size_t hb = (size_t)mt * 128;
  #pragma unroll
  for (int n = 0; n < 4; ++n){
    int nc = n0 + wc * 64 + n * 16 + fr;
    float bv = b1[(size_t)e * H_ + nc];
    #pragma unroll
    for (int m = 0; m < 4; ++m){
      int rbase = wr * 64 + m * 16 + fq * 4;
      #pragma unroll
      for (int r = 0; r < 4; ++r){
        float v = acc[m][n][r] + bv;
        h[(hb + rbase + r) * H_ + nc] = f2bf(v > 0.f ? v : 0.f);
      }
    }
  }
}

// ---------------- GEMM2: out[tok] += p * (h @ W2[e])  (M=pairs, N=1024, K=4096) ----------------
__global__ __launch_bounds__(256) void gemm2(
    const ushort* __restrict__ h, const ushort* __restrict__ w2t,
    float* __restrict__ out,
    const int* __restrict__ texp, const int* __restrict__ tpos,
    const int* __restrict__ btok, const float* __restrict__ bprob,
    const int* __restrict__ meta)
{
  __shared__ ushort Al[2][128 * 32];
  __shared__ ushort Bl[2][128 * 32];
  __shared__ int toks[128];
  __shared__ float probs[128];
  int mt = blockIdx.x;
  if (mt >= meta[0]) return;
  int tid = threadIdx.x, lane = tid & 63, wave = tid >> 6;
  int e = texp[mt], pb = tpos[mt];
  int n0 = blockIdx.y * 128;
  if (tid < 128){
    toks[tid]  = btok[e * CAP + pb + tid];
    probs[tid] = bprob[e * CAP + pb + tid];
  }
  __syncthreads();

  int wr = wave >> 1, wc = wave & 1;
  int fr = lane & 15, kg = lane >> 4;
  const ushort* Bb = w2t + ((size_t)e * C_ + n0) * H_;
  const ushort* Ab = h + (size_t)mt * 128 * H_;

  const ushort* pA[2]; const ushort* pB[2];
  #pragma unroll
  for (int i = 0; i < 2; ++i){
    int ch = i * 256 + tid;
    pA[i] = Ab + (size_t)(ch >> 2) * H_ + (ch & 3) * 8;
    pB[i] = Bb + (size_t)(ch >> 2) * H_ + (ch & 3) * 8;
  }

  f32x4 acc[4][4];
  #pragma unroll
  for (int m = 0; m < 4; ++m)
    #pragma unroll
    for (int n = 0; n < 4; ++n) acc[m][n] = 0.f;

  #pragma unroll
  for (int i = 0; i < 2; ++i){
    int ch = i * 256 + tid;
    async16(pA[i], &Al[0][ch * 8]);
    async16(pB[i], &Bl[0][ch * 8]);
  }
  __syncthreads();

  const int NT = H_ / 32;
  int cur = 0;
  for (int t = 0; t < NT - 1; ++t){
    int k0n = (t + 1) * 32;
    #pragma unroll
    for (int i = 0; i < 2; ++i){
      int ch = i * 256 + tid;
      async16(pA[i] + k0n, &Al[cur ^ 1][ch * 8]);
      async16(pB[i] + k0n, &Bl[cur ^ 1][ch * 8]);
    }
    bf16x8 af[4], bfr[4];
    #pragma unroll
    for (int m = 0; m < 4; ++m) af[m]  = *(const bf16x8*)(&Al[cur][(wr * 64 + m * 16 + fr) * 32 + kg * 8]);
    #pragma unroll
    for (int n = 0; n < 4; ++n) bfr[n] = *(const bf16x8*)(&Bl[cur][(wc * 64 + n * 16 + fr) * 32 + kg * 8]);
    #pragma unroll
    for (int m = 0; m < 4; ++m)
      #pragma unroll
      for (int n = 0; n < 4; ++n)
        acc[m][n] = __builtin_amdgcn_mfma_f32_16x16x32_bf16(af[m], bfr[n], acc[m][n], 0, 0, 0);
    __syncthreads();
    cur ^= 1;
  }
  {
    bf16x8 af[4], bfr[4];
    #pragma unroll
    for (int m = 0; m < 4; ++m) af[m]  = *(const bf16x8*)(&Al[cur][(wr * 64 + m * 16 + fr) * 32 + kg * 8]);
    #pragma unroll
    for (int n = 0; n < 4; ++n) bfr[n] = *(const bf16x8*)(&Bl[cur][(wc * 64 + n * 16 + fr) * 32 + kg * 8]);
    #pragma unroll
    for (int m = 0; m < 4; ++m)
      #pragma unroll
      for (int n = 0; n < 4; ++n)
        acc[m][n] = __builtin_amdgcn_mfma_f32_16x16x32_bf16(af[m], bfr[n], acc[m][n], 0, 0, 0);
  }

  int fq = lane >> 4;
  #pragma unroll
  for (int n = 0; n < 4; ++n){
    int nc = n0 + wc * 64 + n * 16 + fr;
    #pragma unroll
    for (int m = 0; m < 4; ++m){
      int rbase = wr * 64 + m * 16 + fq * 4;
      #pragma unroll
      for (int r = 0; r < 4; ++r){
        int row = rbase + r;
        atomicAdd(out + (size_t)toks[row] * C_ + nc, probs[row] * acc[m][n][r]);
      }
    }
  }
}

// ---------------- launch ----------------
extern "C" void kernel_launch(void* const* d_in, const int* in_sizes, int n_in,
                              void* d_out, int out_size, void* d_ws, size_t ws_size,
                              hipStream_t stream)
{
  const float* x  = (const float*)d_in[0];
  const float* W1 = (const float*)d_in[1];
  const float* b1 = (const float*)d_in[2];
  const float* W2 = (const float*)d_in[3];
  const float* b2 = (const float*)d_in[4];
  const float* Wg = (const float*)d_in[5];
  const float* bg = (const float*)d_in[6];
  float* out = (float*)d_out;

  char* ws = (char*)d_ws;
  size_t off = 0;
  auto alloc = [&](size_t b){ size_t r = off; off += (b + 4095) & ~(size_t)4095; return r; };
  int*    counts = (int*)   (ws + alloc(E_ * 4));
  int*    meta   = (int*)   (ws + alloc(64));
  int*    texp   = (int*)   (ws + alloc(MT_MAX * 4));
  int*    tpos   = (int*)   (ws + alloc(MT_MAX * 4));
  int*    btok   = (int*)   (ws + alloc((size_t)E_ * CAP * 4));
  float*  bprob  = (float*) (ws + alloc((size_t)E_ * CAP * 4));
  ushort* x16    = (ushort*)(ws + alloc((size_t)NTOK * C_ * 2));
  ushort* w1t    = (ushort*)(ws + alloc((size_t)E_ * C_ * H_ * 2));
  ushort* w2t    = (ushort*)(ws + alloc((size_t)E_ * C_ * H_ * 2));
  ushort* h      = (ushort*)(ws + alloc((size_t)MT_MAX * 128 * H_ * 2));
  (void)ws_size; (void)in_sizes; (void)n_in; (void)out_size;

  zero_counts<<<dim3(1), dim3(64), 0, stream>>>(counts);
  gate_kernel<<<dim3(NTOK / 4), dim3(256), 0, stream>>>(x, Wg, bg, b2, out, counts, btok, bprob, x16);
  transpose_w<<<dim3(H_ / 64, C_ / 64, E_), dim3(256), 0, stream>>>(W1, w1t, C_, H_);
  transpose_w<<<dim3(C_ / 64, H_ / 64, E_), dim3(256), 0, stream>>>(W2, w2t, H_, C_);
  setup_kernel<<<dim3(1), dim3(256), 0, stream>>>(counts, meta, texp, tpos, btok, bprob);
  gemm1<<<dim3(MT_MAX, H_ / 128), dim3(256), 0, stream>>>(x16, w1t, b1, h, texp, tpos, btok, meta);
  gemm2<<<dim3(MT_MAX, C_ / 128), dim3(256), 0, stream>>>(h, w2t, out, texp, tpos, btok, bprob, meta);
}

// Round 4
// 1086.936 us; speedup vs baseline: 1.0743x; 1.0229x over previous
//
#include <hip/hip_runtime.h>
#include <hip/hip_bf16.h>
#include <stdint.h>

#define E_    8
#define C_    1024
#define H_    4096
#define NTOK  8192
#define CAP   8192
#define MT_MAX 136
#define NB1   (MT_MAX * (H_ / 128))   // 4352, %8==0
#define NB2   (MT_MAX * (C_ / 128))   // 1088, %8==0

typedef __attribute__((ext_vector_type(8))) short bf16x8;
typedef __attribute__((ext_vector_type(4))) float f32x4;

__device__ __forceinline__ ushort f2bf(float f){
  union { float f; uint32_t u; } v; v.f = f;
  uint32_t r = v.u + 0x7fffu + ((v.u >> 16) & 1u);
  return (ushort)(r >> 16);
}

__device__ __forceinline__ void async16(const ushort* g, ushort* l){
  __builtin_amdgcn_global_load_lds(
      (const __attribute__((address_space(1))) void*)g,
      (__attribute__((address_space(3))) void*)l, 16, 0, 0);
}

// ---------------- zero counts ----------------
__global__ void zero_counts(int* counts){
  if (threadIdx.x < E_) counts[threadIdx.x] = 0;
}

// ---------------- gating: scores, softmax, top2, bucket push, out init, x->bf16 ----------------
__global__ __launch_bounds__(256) void gate_kernel(
    const float* __restrict__ x, const float* __restrict__ Wg,
    const float* __restrict__ bg, const float* __restrict__ b2,
    float* __restrict__ out, int* __restrict__ counts,
    int* __restrict__ btok, float* __restrict__ bprob,
    ushort* __restrict__ x16)
{
  int wave = threadIdx.x >> 6, lane = threadIdx.x & 63;
  int t = blockIdx.x * 4 + wave;
  const float* xr = x + (size_t)t * C_;
  ushort* x16r = x16 + (size_t)t * C_;

  float s[E_];
  #pragma unroll
  for (int e = 0; e < E_; ++e) s[e] = 0.f;
  for (int j = 0; j < 16; ++j){
    int c = j * 64 + lane;
    float xv = xr[c];
    x16r[c] = f2bf(xv);              // fused x fp32->bf16 conversion
    const float* wr = Wg + c * E_;
    #pragma unroll
    for (int e = 0; e < E_; ++e) s[e] += xv * wr[e];
  }
  #pragma unroll
  for (int e = 0; e < E_; ++e){
    float v = s[e];
    for (int o = 32; o; o >>= 1) v += __shfl_xor(v, o);
    s[e] = v + bg[e];
  }
  // softmax over 8
  float mx = s[0];
  #pragma unroll
  for (int e = 1; e < E_; ++e) mx = fmaxf(mx, s[e]);
  float g[E_]; float sum = 0.f;
  #pragma unroll
  for (int e = 0; e < E_; ++e){ g[e] = expf(s[e] - mx); sum += g[e]; }
  float inv = 1.f / sum;
  #pragma unroll
  for (int e = 0; e < E_; ++e) g[e] *= inv;
  // top-2 (ties -> lower index, matching jax.lax.top_k)
  int e0 = 0; float v0 = g[0];
  #pragma unroll
  for (int e = 1; e < E_; ++e) if (g[e] > v0){ v0 = g[e]; e0 = e; }
  int e1 = -1; float v1 = -1.f;
  #pragma unroll
  for (int e = 0; e < E_; ++e){ if (e == e0) continue; if (g[e] > v1){ v1 = g[e]; e1 = e; } }
  // renormalized softmax over the two selected probabilities
  float q  = expf(v1 - v0);
  float p0 = 1.f / (1.f + q);
  float p1 = q / (1.f + q);

  // out init: out[t,:] = p0*b2[e0,:] + p1*b2[e1,:]
  const float* b2a = b2 + (size_t)e0 * C_;
  const float* b2b = b2 + (size_t)e1 * C_;
  float* orow = out + (size_t)t * C_;
  for (int j = 0; j < 16; ++j){
    int c = j * 64 + lane;
    orow[c] = p0 * b2a[c] + p1 * b2b[c];
  }
  if (lane == 0){
    int p = atomicAdd(&counts[e0], 1);
    btok[e0 * CAP + p] = t; bprob[e0 * CAP + p] = p0;
    p = atomicAdd(&counts[e1], 1);
    btok[e1 * CAP + p] = t; bprob[e1 * CAP + p] = p1;
  }
}

// ---------------- W transpose + convert: in fp32 [E][R][S] -> out bf16 [E][S][R] ----------------
__global__ __launch_bounds__(256) void transpose_w(const float* __restrict__ in, ushort* __restrict__ out,
                                                   int R, int S){
  __shared__ float t[64][65];
  int e  = blockIdx.z;
  int s0 = blockIdx.x * 64, r0 = blockIdx.y * 64;
  const float* ip = in  + (size_t)e * R * S;
  ushort*      op = out + (size_t)e * R * S;
  int cr = threadIdx.x >> 6;     // 0..3
  int cc = threadIdx.x & 63;
  #pragma unroll
  for (int i = 0; i < 16; ++i){
    int r = i * 4 + cr;
    t[r][cc] = ip[(size_t)(r0 + r) * S + s0 + cc];
  }
  __syncthreads();
  #pragma unroll
  for (int i = 0; i < 16; ++i){
    int s = i * 4 + cr;
    op[(size_t)(s0 + s) * R + r0 + cc] = f2bf(t[cc][s]);
  }
}

// ---------------- setup: prefix tiles, tile table, bucket padding ----------------
__global__ void setup_kernel(const int* __restrict__ counts, int* __restrict__ meta,
                             int* __restrict__ texp, int* __restrict__ tpos,
                             int* __restrict__ btok, float* __restrict__ bprob){
  __shared__ int toff[E_ + 1];
  if (threadIdx.x == 0){
    int to = 0;
    for (int e = 0; e < E_; ++e){ toff[e] = to; to += (counts[e] + 127) >> 7; }
    toff[E_] = to; meta[0] = to;
  }
  __syncthreads();
  int total = toff[E_];
  for (int i = threadIdx.x; i < MT_MAX; i += 256){
    if (i < total){
      int e = 0;
      while (e < E_ - 1 && i >= toff[e + 1]) ++e;
      texp[i] = e; tpos[i] = (i - toff[e]) * 128;
    } else { texp[i] = 0; tpos[i] = 0; }
  }
  for (int j = threadIdx.x; j < E_ * 128; j += 256){
    int e = j >> 7, r = j & 127;
    int c = counts[e];
    int padded = ((c + 127) >> 7) << 7;
    int pos = c + r;
    if (pos < padded){ btok[e * CAP + pos] = 0; bprob[e * CAP + pos] = 0.f; }
  }
}

// ---------------- GEMM1: h = relu(gather(x16) @ W1[e] + b1[e])  (M=pairs, N=4096, K=1024) ----------------
// double-buffered LDS + chunked XCD swizzle (T1): same-B-panel blocks stay on one XCD's L2
__global__ __launch_bounds__(256) void gemm1(
    const ushort* __restrict__ x16, const ushort* __restrict__ w1t,
    const float* __restrict__ b1, ushort* __restrict__ h,
    const int* __restrict__ texp, const int* __restrict__ tpos,
    const int* __restrict__ btok, const int* __restrict__ meta)
{
  __shared__ ushort Al[2][128 * 32];
  __shared__ ushort Bl[2][128 * 32];
  __shared__ int toks[128];
  // bijective chunked XCD swizzle (NB1 % 8 == 0)
  int bid = blockIdx.x;
  int work = (bid & 7) * (NB1 / 8) + (bid >> 3);
  int y = work / MT_MAX, mt = work % MT_MAX;
  if (mt >= meta[0]) return;
  int tid = threadIdx.x, lane = tid & 63, wave = tid >> 6;
  int e = texp[mt], pb = tpos[mt];
  int n0 = y * 128;
  if (tid < 128) toks[tid] = btok[e * CAP + pb + tid];
  __syncthreads();

  int wr = wave >> 1, wc = wave & 1;
  int fr = lane & 15, kg = lane >> 4;
  const ushort* Bb = w1t + ((size_t)e * H_ + n0) * C_;

  const ushort* pA[2]; const ushort* pB[2];
  #pragma unroll
  for (int i = 0; i < 2; ++i){
    int ch = i * 256 + tid;
    pA[i] = x16 + (size_t)toks[ch >> 2] * C_ + (ch & 3) * 8;
    pB[i] = Bb  + (size_t)(ch >> 2)     * C_ + (ch & 3) * 8;
  }

  f32x4 acc[4][4];
  #pragma unroll
  for (int m = 0; m < 4; ++m)
    #pragma unroll
    for (int n = 0; n < 4; ++n) acc[m][n] = 0.f;

  #pragma unroll
  for (int i = 0; i < 2; ++i){
    int ch = i * 256 + tid;
    async16(pA[i], &Al[0][ch * 8]);
    async16(pB[i], &Bl[0][ch * 8]);
  }
  __syncthreads();

  const int NT = C_ / 32;
  int cur = 0;
  for (int t = 0; t < NT - 1; ++t){
    int k0n = (t + 1) * 32;
    #pragma unroll
    for (int i = 0; i < 2; ++i){
      int ch = i * 256 + tid;
      async16(pA[i] + k0n, &Al[cur ^ 1][ch * 8]);
      async16(pB[i] + k0n, &Bl[cur ^ 1][ch * 8]);
    }
    bf16x8 af[4], bfr[4];
    #pragma unroll
    for (int m = 0; m < 4; ++m) af[m]  = *(const bf16x8*)(&Al[cur][(wr * 64 + m * 16 + fr) * 32 + kg * 8]);
    #pragma unroll
    for (int n = 0; n < 4; ++n) bfr[n] = *(const bf16x8*)(&Bl[cur][(wc * 64 + n * 16 + fr) * 32 + kg * 8]);
    #pragma unroll
    for (int m = 0; m < 4; ++m)
      #pragma unroll
      for (int n = 0; n < 4; ++n)
        acc[m][n] = __builtin_amdgcn_mfma_f32_16x16x32_bf16(af[m], bfr[n], acc[m][n], 0, 0, 0);
    __syncthreads();
    cur ^= 1;
  }
  {
    bf16x8 af[4], bfr[4];
    #pragma unroll
    for (int m = 0; m < 4; ++m) af[m]  = *(const bf16x8*)(&Al[cur][(wr * 64 + m * 16 + fr) * 32 + kg * 8]);
    #pragma unroll
    for (int n = 0; n < 4; ++n) bfr[n] = *(const bf16x8*)(&Bl[cur][(wc * 64 + n * 16 + fr) * 32 + kg * 8]);
    #pragma unroll
    for (int m = 0; m < 4; ++m)
      #pragma unroll
      for (int n = 0; n < 4; ++n)
        acc[m][n] = __builtin_amdgcn_mfma_f32_16x16x32_bf16(af[m], bfr[n], acc[m][n], 0, 0, 0);
  }

  int fq = lane >> 4;
  size_t hb = (size_t)mt * 128;
  #pragma unroll
  for (int n = 0; n < 4; ++n){
    int nc = n0 + wc * 64 + n * 16 + fr;
    float bv = b1[(size_t)e * H_ + nc];
    #pragma unroll
    for (int m = 0; m < 4; ++m){
      int rbase = wr * 64 + m * 16 + fq * 4;
      #pragma unroll
      for (int r = 0; r < 4; ++r){
        float v = acc[m][n][r] + bv;
        h[(hb + rbase + r) * H_ + nc] = f2bf(v > 0.f ? v : 0.f);
      }
    }
  }
}

// ---------------- GEMM2: out[tok] += p * (h @ W2[e])  (M=pairs, N=1024, K=4096) ----------------
__global__ __launch_bounds__(256) void gemm2(
    const ushort* __restrict__ h, const ushort* __restrict__ w2t,
    float* __restrict__ out,
    const int* __restrict__ texp, const int* __restrict__ tpos,
    const int* __restrict__ btok, const float* __restrict__ bprob,
    const int* __restrict__ meta)
{
  __shared__ ushort Al[2][128 * 32];
  __shared__ ushort Bl[2][128 * 32];
  __shared__ int toks[128];
  __shared__ float probs[128];
  // bijective chunked XCD swizzle (NB2 % 8 == 0): XCD k owns N-panel y=k, sweeps mt in order
  int bid = blockIdx.x;
  int work = (bid & 7) * (NB2 / 8) + (bid >> 3);
  int y = work / MT_MAX, mt = work % MT_MAX;
  if (mt >= meta[0]) return;
  int tid = threadIdx.x, lane = tid & 63, wave = tid >> 6;
  int e = texp[mt], pb = tpos[mt];
  int n0 = y * 128;
  if (tid < 128){
    toks[tid]  = btok[e * CAP + pb + tid];
    probs[tid] = bprob[e * CAP + pb + tid];
  }
  __syncthreads();

  int wr = wave >> 1, wc = wave & 1;
  int fr = lane & 15, kg = lane >> 4;
  const ushort* Bb = w2t + ((size_t)e * C_ + n0) * H_;
  const ushort* Ab = h + (size_t)mt * 128 * H_;

  const ushort* pA[2]; const ushort* pB[2];
  #pragma unroll
  for (int i = 0; i < 2; ++i){
    int ch = i * 256 + tid;
    pA[i] = Ab + (size_t)(ch >> 2) * H_ + (ch & 3) * 8;
    pB[i] = Bb + (size_t)(ch >> 2) * H_ + (ch & 3) * 8;
  }

  f32x4 acc[4][4];
  #pragma unroll
  for (int m = 0; m < 4; ++m)
    #pragma unroll
    for (int n = 0; n < 4; ++n) acc[m][n] = 0.f;

  #pragma unroll
  for (int i = 0; i < 2; ++i){
    int ch = i * 256 + tid;
    async16(pA[i], &Al[0][ch * 8]);
    async16(pB[i], &Bl[0][ch * 8]);
  }
  __syncthreads();

  const int NT = H_ / 32;
  int cur = 0;
  for (int t = 0; t < NT - 1; ++t){
    int k0n = (t + 1) * 32;
    #pragma unroll
    for (int i = 0; i < 2; ++i){
      int ch = i * 256 + tid;
      async16(pA[i] + k0n, &Al[cur ^ 1][ch * 8]);
      async16(pB[i] + k0n, &Bl[cur ^ 1][ch * 8]);
    }
    bf16x8 af[4], bfr[4];
    #pragma unroll
    for (int m = 0; m < 4; ++m) af[m]  = *(const bf16x8*)(&Al[cur][(wr * 64 + m * 16 + fr) * 32 + kg * 8]);
    #pragma unroll
    for (int n = 0; n < 4; ++n) bfr[n] = *(const bf16x8*)(&Bl[cur][(wc * 64 + n * 16 + fr) * 32 + kg * 8]);
    #pragma unroll
    for (int m = 0; m < 4; ++m)
      #pragma unroll
      for (int n = 0; n < 4; ++n)
        acc[m][n] = __builtin_amdgcn_mfma_f32_16x16x32_bf16(af[m], bfr[n], acc[m][n], 0, 0, 0);
    __syncthreads();
    cur ^= 1;
  }
  {
    bf16x8 af[4], bfr[4];
    #pragma unroll
    for (int m = 0; m < 4; ++m) af[m]  = *(const bf16x8*)(&Al[cur][(wr * 64 + m * 16 + fr) * 32 + kg * 8]);
    #pragma unroll
    for (int n = 0; n < 4; ++n) bfr[n] = *(const bf16x8*)(&Bl[cur][(wc * 64 + n * 16 + fr) * 32 + kg * 8]);
    #pragma unroll
    for (int m = 0; m < 4; ++m)
      #pragma unroll
      for (int n = 0; n < 4; ++n)
        acc[m][n] = __builtin_amdgcn_mfma_f32_16x16x32_bf16(af[m], bfr[n], acc[m][n], 0, 0, 0);
  }

  int fq = lane >> 4;
  #pragma unroll
  for (int n = 0; n < 4; ++n){
    int nc = n0 + wc * 64 + n * 16 + fr;
    #pragma unroll
    for (int m = 0; m < 4; ++m){
      int rbase = wr * 64 + m * 16 + fq * 4;
      #pragma unroll
      for (int r = 0; r < 4; ++r){
        int row = rbase + r;
        atomicAdd(out + (size_t)toks[row] * C_ + nc, probs[row] * acc[m][n][r]);
      }
    }
  }
}

// ---------------- launch ----------------
extern "C" void kernel_launch(void* const* d_in, const int* in_sizes, int n_in,
                              void* d_out, int out_size, void* d_ws, size_t ws_size,
                              hipStream_t stream)
{
  const float* x  = (const float*)d_in[0];
  const float* W1 = (const float*)d_in[1];
  const float* b1 = (const float*)d_in[2];
  const float* W2 = (const float*)d_in[3];
  const float* b2 = (const float*)d_in[4];
  const float* Wg = (const float*)d_in[5];
  const float* bg = (const float*)d_in[6];
  float* out = (float*)d_out;

  char* ws = (char*)d_ws;
  size_t off = 0;
  auto alloc = [&](size_t b){ size_t r = off; off += (b + 4095) & ~(size_t)4095; return r; };
  int*    counts = (int*)   (ws + alloc(E_ * 4));
  int*    meta   = (int*)   (ws + alloc(64));
  int*    texp   = (int*)   (ws + alloc(MT_MAX * 4));
  int*    tpos   = (int*)   (ws + alloc(MT_MAX * 4));
  int*    btok   = (int*)   (ws + alloc((size_t)E_ * CAP * 4));
  float*  bprob  = (float*) (ws + alloc((size_t)E_ * CAP * 4));
  ushort* x16    = (ushort*)(ws + alloc((size_t)NTOK * C_ * 2));
  ushort* w1t    = (ushort*)(ws + alloc((size_t)E_ * C_ * H_ * 2));
  ushort* w2t    = (ushort*)(ws + alloc((size_t)E_ * C_ * H_ * 2));
  ushort* h      = (ushort*)(ws + alloc((size_t)MT_MAX * 128 * H_ * 2));
  (void)ws_size; (void)in_sizes; (void)n_in; (void)out_size;

  zero_counts<<<dim3(1), dim3(64), 0, stream>>>(counts);
  gate_kernel<<<dim3(NTOK / 4), dim3(256), 0, stream>>>(x, Wg, bg, b2, out, counts, btok, bprob, x16);
  transpose_w<<<dim3(H_ / 64, C_ / 64, E_), dim3(256), 0, stream>>>(W1, w1t, C_, H_);
  transpose_w<<<dim3(C_ / 64, H_ / 64, E_), dim3(256), 0, stream>>>(W2, w2t, H_, C_);
  setup_kernel<<<dim3(1), dim3(256), 0, stream>>>(counts, meta, texp, tpos, btok, bprob);
  gemm1<<<dim3(NB1), dim3(256), 0, stream>>>(x16, w1t, b1, h, texp, tpos, btok, meta);
  gemm2<<<dim3(NB2), dim3(256), 0, stream>>>(h, w2t, out, texp, tpos, btok, bprob, meta);
}